// Round 1
// baseline (216.932 us; speedup 1.0000x reference)
//
#include <hip/hip_runtime.h>

// Problem constants (fixed by the reference):
//   pred/target: (B=2, C=1, H=192, W=192, D=192) float32, D contiguous.
//   5x5x5 box mean (zero pad), NCC^2, loss = -mean(ncc).
#define HH 192
#define WW 192
#define DD 192
#define BB 2
#define KK 5
#define TX 16          // tile along D (contiguous)
#define TY 16          // tile along W
#define HCHUNK 48      // h-slab per block (192/4)

__global__ __launch_bounds__(256)
void lncc_fused_kernel(const float* __restrict__ pred,
                       const float* __restrict__ targ,
                       double* __restrict__ acc_out) {
    __shared__ float sP[TY + 4][TX + 4];        // 20x20 raw pred slice
    __shared__ float sT[TY + 4][TX + 4];        // 20x20 raw targ slice
    __shared__ float sR[5][TY + 4][TX];         // d-summed products, 5 quantities
    __shared__ float wsum[4];

    const int tx = threadIdx.x;
    const int ty = threadIdx.y;
    const int tid = ty * TX + tx;

    const int d0 = blockIdx.x * TX;
    const int w0 = blockIdx.y * TY;
    const int bz = blockIdx.z;
    const int b  = bz >> 2;                     // batch
    const int h0 = (bz & 3) * HCHUNK;           // h-slab start
    const size_t base = (size_t)b * HH * WW * DD;

    // Per-thread ring buffer over h: ring[q][i], i=0 oldest.
    float ring[5][5];
#pragma unroll
    for (int q = 0; q < 5; ++q)
#pragma unroll
        for (int i = 0; i < 5; ++i) ring[q][i] = 0.0f;

    float acc = 0.0f;

    for (int h = h0 - 2; h <= h0 + HCHUNK + 1; ++h) {
        const bool hin = (h >= 0) && (h < HH);
        // ---- stage raw slice (with +/-2 halo in w,d) ----
        for (int p = tid; p < (TY + 4) * (TX + 4); p += 256) {
            const int yy = p / (TX + 4);
            const int xx = p % (TX + 4);
            const int w = w0 - 2 + yy;
            const int d = d0 - 2 + xx;
            float pv = 0.0f, tv = 0.0f;
            if (hin && (unsigned)w < (unsigned)WW && (unsigned)d < (unsigned)DD) {
                const size_t idx = base + ((size_t)h * WW + w) * DD + d;
                pv = pred[idx];
                tv = targ[idx];
            }
            sP[yy][xx] = pv;
            sT[yy][xx] = tv;
        }
        __syncthreads();

        // ---- d-direction 5-sums of the 5 products ----
        for (int p = tid; p < (TY + 4) * TX; p += 256) {
            const int yy = p / TX;
            const int xx = p % TX;
            float s0 = 0.f, s1 = 0.f, s2 = 0.f, s3 = 0.f, s4 = 0.f;
#pragma unroll
            for (int dx = 0; dx < KK; ++dx) {
                const float pv = sP[yy][xx + dx];
                const float tv = sT[yy][xx + dx];
                s0 += pv;
                s1 += tv;
                s2 += pv * pv;
                s3 += tv * tv;
                s4 += pv * tv;
            }
            sR[0][yy][xx] = s0;
            sR[1][yy][xx] = s1;
            sR[2][yy][xx] = s2;
            sR[3][yy][xx] = s3;
            sR[4][yy][xx] = s4;
        }
        __syncthreads();

        // ---- w-direction 5-sums -> push into h ring ----
#pragma unroll
        for (int q = 0; q < 5; ++q) {
#pragma unroll
            for (int i = 0; i < 4; ++i) ring[q][i] = ring[q][i + 1];
            ring[q][4] = sR[q][ty][tx] + sR[q][ty + 1][tx] + sR[q][ty + 2][tx]
                       + sR[q][ty + 3][tx] + sR[q][ty + 4][tx];
        }

        // ---- emit output voxel (h-2, w0+ty, d0+tx) ----
        const int hout = h - 2;
        if (hout >= h0 && hout < h0 + HCHUNK) {
            float S[5];
#pragma unroll
            for (int q = 0; q < 5; ++q)
                S[q] = ring[q][0] + ring[q][1] + ring[q][2] + ring[q][3] + ring[q][4];
            const float inv = 1.0f / 125.0f;
            const float uI = S[0] * inv;
            const float uJ = S[1] * inv;
            const float I2 = S[2] * inv;
            const float J2 = S[3] * inv;
            const float IJ = S[4] * inv;
            const float cross = IJ - uI * uJ;
            const float vi = I2 - uI * uI;
            const float vj = J2 - uJ * uJ;
            const float ncc = (cross * cross) / (vi * vj + 1e-5f);
            acc += ncc;
        }
        __syncthreads();   // protect sR before next iteration rewrites it
    }

    // ---- block reduction ----
#pragma unroll
    for (int off = 32; off > 0; off >>= 1) acc += __shfl_down(acc, off, 64);
    const int wid = tid >> 6;
    const int lane = tid & 63;
    if (lane == 0) wsum[wid] = acc;
    __syncthreads();
    if (tid == 0) {
        const float s = wsum[0] + wsum[1] + wsum[2] + wsum[3];
        atomicAdd(acc_out, (double)s);
    }
}

__global__ void lncc_finalize_kernel(const double* __restrict__ acc,
                                     float* __restrict__ out) {
    const double n = (double)BB * HH * WW * DD;
    out[0] = (float)(-acc[0] / n);
}

extern "C" void kernel_launch(void* const* d_in, const int* in_sizes, int n_in,
                              void* d_out, int out_size, void* d_ws, size_t ws_size,
                              hipStream_t stream) {
    const float* pred = (const float*)d_in[0];
    const float* targ = (const float*)d_in[1];
    float* out = (float*)d_out;
    double* acc = (double*)d_ws;

    hipMemsetAsync(d_ws, 0, sizeof(double), stream);

    dim3 grid(DD / TX, WW / TY, BB * (HH / HCHUNK));   // 12 x 12 x 8
    dim3 block(TX, TY, 1);                             // 256 threads
    lncc_fused_kernel<<<grid, block, 0, stream>>>(pred, targ, acc);
    lncc_finalize_kernel<<<1, 1, 0, stream>>>(acc, out);
}

// Round 2
// 206.083 us; speedup vs baseline: 1.0526x; 1.0526x over previous
//
#include <hip/hip_runtime.h>

// pred/target: (B=2, C=1, H=192, W=192, D=192) fp32, D contiguous.
// 5x5x5 box mean (zero pad), ncc = cross^2/(vi*vj+1e-5), loss = -mean(ncc).
#define HH 192
#define WW 192
#define DD 192
#define BB 2
#define TX 16            // tile along D (contiguous)
#define TY 16            // tile along W
#define HCHUNK 24        // h-slab per block -> grid 12*12*16 = 2304 = 9 blocks/CU, even
#define RY (TY + 4)      // 20 staged rows (w halo)
#define RPX ((TX + 4)/2) // 10 float2-pairs along d (d0-2 is 8B-aligned)
#define NSTAGE (RY * RPX)     // 200 staging items
#define NDPAIR (RY * (TX/2))  // 160 d-sum pair items
#define SLICES (HCHUNK + 4)   // 28 h iterations

__global__ __launch_bounds__(256)
void lncc_fused_kernel(const float* __restrict__ pred,
                       const float* __restrict__ targ,
                       double* __restrict__ acc_out) {
    // Interleaved raw slice: cell = (p[2k], t[2k], p[2k+1], t[2k+1]); double-buffered.
    __shared__ float4 sPT[2][RY][RPX];
    // d-summed products: (sI,sJ,sII,sJJ) packed + sIJ separate.
    __shared__ float4 sR4[RY][TX];
    __shared__ float  sRe[RY][TX];
    __shared__ float  wpart[4];

    const int tx = threadIdx.x;
    const int ty = threadIdx.y;
    const int tid = ty * TX + tx;

    const int d0 = blockIdx.x * TX;
    const int w0 = blockIdx.y * TY;
    const int bz = blockIdx.z;
    const int b  = bz >> 3;
    const int h0 = (bz & 7) * HCHUNK;
    const long long base = (long long)b * ((long long)HH * WW * DD);

    // Staging assignment (one float2-pair of pred+targ per thread, tid < 200)
    const int syy = tid / RPX;
    const int spx = tid - syy * RPX;
    const int sw  = w0 - 2 + syy;
    const int sd  = d0 - 2 + 2 * spx;
    const bool s_ok = (tid < NSTAGE) & ((unsigned)sw < (unsigned)WW) & ((unsigned)sd < (unsigned)DD);
    const long long spos = base + (long long)sw * DD + sd;

    // d-sum assignment (one pair of adjacent cells per thread, tid < 160)
    const int dyy = tid / (TX / 2);
    const int dxh = tid - dyy * (TX / 2);
    const bool d_ok = (tid < NDPAIR);

    // Per-thread h ring buffer: 5 quantities x 5 slices.
    float ring[5][5];
#pragma unroll
    for (int q = 0; q < 5; ++q)
#pragma unroll
        for (int i = 0; i < 5; ++i) ring[q][i] = 0.0f;

    float acc = 0.0f;

    for (int it = 0; it < SLICES; ++it) {
        const int h = h0 - 2 + it;
        const int buf = it & 1;
        const bool hin = (h >= 0) & (h < HH);

        // ---- stage raw slice (float2 global loads, b128 LDS write) ----
        float2 pv = make_float2(0.f, 0.f), tv = make_float2(0.f, 0.f);
        if (s_ok & hin) {
            const long long idx = spos + (long long)h * (WW * DD);
            pv = *(const float2*)(pred + idx);
            tv = *(const float2*)(targ + idx);
        }
        if (tid < NSTAGE)
            sPT[buf][syy][spx] = make_float4(pv.x, tv.x, pv.y, tv.y);
        __syncthreads();

        // ---- d-direction 5-window sums, 2 cells per thread ----
        if (d_ok) {
            const float4 c0 = sPT[buf][dyy][dxh];
            const float4 c1 = sPT[buf][dyy][dxh + 1];
            const float4 c2 = sPT[buf][dyy][dxh + 2];
            const float p0 = c0.x, q0 = c0.y, p1 = c0.z, q1 = c0.w;
            const float p2 = c1.x, q2 = c1.y, p3 = c1.z, q3 = c1.w;
            const float p4 = c2.x, q4 = c2.y, p5 = c2.z, q5 = c2.w;
            const float a0 = p0+p1+p2+p3+p4;
            const float a1 = q0+q1+q2+q3+q4;
            const float a2 = p0*p0+p1*p1+p2*p2+p3*p3+p4*p4;
            const float a3 = q0*q0+q1*q1+q2*q2+q3*q3+q4*q4;
            const float a4 = p0*q0+p1*q1+p2*q2+p3*q3+p4*q4;
            const float b0 = p1+p2+p3+p4+p5;
            const float b1 = q1+q2+q3+q4+q5;
            const float b2 = p1*p1+p2*p2+p3*p3+p4*p4+p5*p5;
            const float b3 = q1*q1+q2*q2+q3*q3+q4*q4+q5*q5;
            const float b4 = p1*q1+p2*q2+p3*q3+p4*q4+p5*q5;
            sR4[dyy][2*dxh]     = make_float4(a0, a1, a2, a3);
            sR4[dyy][2*dxh + 1] = make_float4(b0, b1, b2, b3);
            *(float2*)&sRe[dyy][2*dxh] = make_float2(a4, b4);
        }
        __syncthreads();

        // ---- w-direction 5-sums (vector LDS reads) -> h ring ----
        float s0 = 0.f, s1 = 0.f, s2 = 0.f, s3 = 0.f, s4 = 0.f;
#pragma unroll
        for (int i = 0; i < 5; ++i) {
            const float4 v = sR4[ty + i][tx];
            s0 += v.x; s1 += v.y; s2 += v.z; s3 += v.w;
            s4 += sRe[ty + i][tx];
        }
#pragma unroll
        for (int q = 0; q < 5; ++q)
#pragma unroll
            for (int i = 0; i < 4; ++i) ring[q][i] = ring[q][i + 1];
        ring[0][4] = s0; ring[1][4] = s1; ring[2][4] = s2;
        ring[3][4] = s3; ring[4][4] = s4;

        // ---- emit voxel (h-2, w0+ty, d0+tx) ----
        const int hout = h - 2;
        if (hout >= h0 && hout < h0 + HCHUNK) {
            float S[5];
#pragma unroll
            for (int q = 0; q < 5; ++q)
                S[q] = ring[q][0] + ring[q][1] + ring[q][2] + ring[q][3] + ring[q][4];
            const float inv = 1.0f / 125.0f;
            const float uI = S[0] * inv, uJ = S[1] * inv;
            const float I2 = S[2] * inv, J2 = S[3] * inv, IJ = S[4] * inv;
            const float cross = IJ - uI * uJ;
            const float vi = I2 - uI * uI;
            const float vj = J2 - uJ * uJ;
            acc += (cross * cross) / (vi * vj + 1e-5f);
        }
        // no third barrier: sPT is double-buffered; sR rewrite is fenced by
        // the next iteration's first __syncthreads()
    }

    // ---- block reduction, one double atomic per block ----
#pragma unroll
    for (int off = 32; off > 0; off >>= 1) acc += __shfl_down(acc, off, 64);
    const int wid = tid >> 6, lane = tid & 63;
    if (lane == 0) wpart[wid] = acc;
    __syncthreads();
    if (tid == 0)
        atomicAdd(acc_out, (double)(wpart[0] + wpart[1] + wpart[2] + wpart[3]));
}

__global__ void lncc_finalize_kernel(const double* __restrict__ acc,
                                     float* __restrict__ out) {
    const double n = (double)BB * HH * WW * DD;
    out[0] = (float)(-acc[0] / n);
}

extern "C" void kernel_launch(void* const* d_in, const int* in_sizes, int n_in,
                              void* d_out, int out_size, void* d_ws, size_t ws_size,
                              hipStream_t stream) {
    const float* pred = (const float*)d_in[0];
    const float* targ = (const float*)d_in[1];
    float* out = (float*)d_out;
    double* acc = (double*)d_ws;

    hipMemsetAsync(d_ws, 0, sizeof(double), stream);

    dim3 grid(DD / TX, WW / TY, BB * (HH / HCHUNK));   // 12 x 12 x 16 = 2304
    dim3 block(TX, TY, 1);                             // 256 threads
    lncc_fused_kernel<<<grid, block, 0, stream>>>(pred, targ, acc);
    lncc_finalize_kernel<<<1, 1, 0, stream>>>(acc, out);
}

// Round 3
// 191.944 us; speedup vs baseline: 1.1302x; 1.0737x over previous
//
#include <hip/hip_runtime.h>

// pred/target: (B=2, C=1, H=192, W=192, D=192) fp32, D contiguous.
// 5x5x5 box mean (zero pad), ncc = cross^2/(vi*vj+1e-5), loss = -mean(ncc).
#define HH 192
#define WW 192
#define DD 192
#define BB 2
#define TX 16            // tile along D (contiguous)
#define TY 16            // tile along W
#define HCHUNK 28        // h-slab; 7 slabs cover 196>=192 (last clamped)
#define NSLAB 7          // grid = 12*12*14 = 2016 <= 2048 -> single residency wave
#define RY (TY + 4)      // 20 staged rows (w halo)
#define RPX ((TX + 4)/2) // 10 float2-pairs along d
#define PPX (RPX + 1)    // padded row: 11 float4 (stride 44 floats, != 0 mod 32)
#define PR4 (TX + 1)     // padded sR4 row: 17 float4 (stride 68 floats)
#define PRE (TX + 2)     // padded sRe row: 18 floats
#define NSTAGE (RY * RPX)     // 200 staging items
#define NDPAIR (RY * (TX/2))  // 160 d-sum pair items
#define SLICES (HCHUNK + 4)   // 32 h iterations

__global__ __launch_bounds__(256)
void lncc_fused_kernel(const float* __restrict__ pred,
                       const float* __restrict__ targ,
                       double* __restrict__ acc_out) {
    // Interleaved raw slice: cell = (p[2k], t[2k], p[2k+1], t[2k+1]); double-buffered.
    __shared__ float4 sPT[2][RY][PPX];
    // d-summed products: (sI,sJ,sII,sJJ) packed + sIJ separate. Rows padded.
    __shared__ float4 sR4[RY][PR4];
    __shared__ float  sRe[RY][PRE];
    __shared__ float  wpart[4];

    const int tx = threadIdx.x;
    const int ty = threadIdx.y;
    const int tid = ty * TX + tx;

    const int d0 = blockIdx.x * TX;
    const int w0 = blockIdx.y * TY;
    const int bz = blockIdx.z;
    const int b  = bz / NSLAB;
    const int h0 = (bz - b * NSLAB) * HCHUNK;
    const long long base = (long long)b * ((long long)HH * WW * DD);

    // Staging assignment (one float2-pair of pred+targ per thread, tid < 200)
    const int syy = tid / RPX;
    const int spx = tid - syy * RPX;
    const int sw  = w0 - 2 + syy;
    const int sd  = d0 - 2 + 2 * spx;
    const bool s_ok = (tid < NSTAGE) & ((unsigned)sw < (unsigned)WW) & ((unsigned)sd < (unsigned)DD);
    const long long spos = base + (long long)sw * DD + sd;

    // d-sum assignment (one pair of adjacent cells per thread, tid < 160)
    const int dyy = tid / (TX / 2);
    const int dxh = tid - dyy * (TX / 2);
    const bool d_ok = (tid < NDPAIR);

    // Per-thread h ring buffer: 5 quantities x 5 slices.
    float ring[5][5];
#pragma unroll
    for (int q = 0; q < 5; ++q)
#pragma unroll
        for (int i = 0; i < 5; ++i) ring[q][i] = 0.0f;

    float acc = 0.0f;

    for (int it = 0; it < SLICES; ++it) {
        const int h = h0 - 2 + it;
        const int buf = it & 1;
        const bool hin = (h >= 0) & (h < HH);

        // ---- stage raw slice (float2 global loads, b128 LDS write) ----
        float2 pv = make_float2(0.f, 0.f), tv = make_float2(0.f, 0.f);
        if (s_ok & hin) {
            const long long idx = spos + (long long)h * (WW * DD);
            pv = *(const float2*)(pred + idx);
            tv = *(const float2*)(targ + idx);
        }
        if (tid < NSTAGE)
            sPT[buf][syy][spx] = make_float4(pv.x, tv.x, pv.y, tv.y);
        __syncthreads();

        // ---- d-direction 5-window sums, 2 cells per thread ----
        if (d_ok) {
            const float4 c0 = sPT[buf][dyy][dxh];
            const float4 c1 = sPT[buf][dyy][dxh + 1];
            const float4 c2 = sPT[buf][dyy][dxh + 2];
            const float p0 = c0.x, q0 = c0.y, p1 = c0.z, q1 = c0.w;
            const float p2 = c1.x, q2 = c1.y, p3 = c1.z, q3 = c1.w;
            const float p4 = c2.x, q4 = c2.y, p5 = c2.z, q5 = c2.w;
            const float a0 = p0+p1+p2+p3+p4;
            const float a1 = q0+q1+q2+q3+q4;
            const float a2 = p0*p0+p1*p1+p2*p2+p3*p3+p4*p4;
            const float a3 = q0*q0+q1*q1+q2*q2+q3*q3+q4*q4;
            const float a4 = p0*q0+p1*q1+p2*q2+p3*q3+p4*q4;
            const float b0 = p1+p2+p3+p4+p5;
            const float b1 = q1+q2+q3+q4+q5;
            const float b2 = p1*p1+p2*p2+p3*p3+p4*p4+p5*p5;
            const float b3 = q1*q1+q2*q2+q3*q3+q4*q4+q5*q5;
            const float b4 = p1*q1+p2*q2+p3*q3+p4*q4+p5*q5;
            sR4[dyy][2*dxh]     = make_float4(a0, a1, a2, a3);
            sR4[dyy][2*dxh + 1] = make_float4(b0, b1, b2, b3);
            *(float2*)&sRe[dyy][2*dxh] = make_float2(a4, b4);
        }
        __syncthreads();

        // ---- w-direction 5-sums (vector LDS reads) -> h ring ----
        float s0 = 0.f, s1 = 0.f, s2 = 0.f, s3 = 0.f, s4 = 0.f;
#pragma unroll
        for (int i = 0; i < 5; ++i) {
            const float4 v = sR4[ty + i][tx];
            s0 += v.x; s1 += v.y; s2 += v.z; s3 += v.w;
            s4 += sRe[ty + i][tx];
        }
#pragma unroll
        for (int q = 0; q < 5; ++q)
#pragma unroll
            for (int i = 0; i < 4; ++i) ring[q][i] = ring[q][i + 1];
        ring[0][4] = s0; ring[1][4] = s1; ring[2][4] = s2;
        ring[3][4] = s3; ring[4][4] = s4;

        // ---- emit voxel (h-2, w0+ty, d0+tx) ----
        const int hout = h - 2;
        if (hout >= h0 && hout < h0 + HCHUNK && hout < HH) {
            float S[5];
#pragma unroll
            for (int q = 0; q < 5; ++q)
                S[q] = ring[q][0] + ring[q][1] + ring[q][2] + ring[q][3] + ring[q][4];
            const float inv = 1.0f / 125.0f;
            const float uI = S[0] * inv, uJ = S[1] * inv;
            const float I2 = S[2] * inv, J2 = S[3] * inv, IJ = S[4] * inv;
            const float cross = IJ - uI * uJ;
            const float vi = I2 - uI * uI;
            const float vj = J2 - uJ * uJ;
            acc += (cross * cross) / (vi * vj + 1e-5f);
        }
        // no third barrier: sPT is double-buffered; sR rewrite is fenced by
        // the next iteration's first __syncthreads()
    }

    // ---- block reduction, one double atomic per block ----
#pragma unroll
    for (int off = 32; off > 0; off >>= 1) acc += __shfl_down(acc, off, 64);
    const int wid = tid >> 6, lane = tid & 63;
    if (lane == 0) wpart[wid] = acc;
    __syncthreads();
    if (tid == 0)
        atomicAdd(acc_out, (double)(wpart[0] + wpart[1] + wpart[2] + wpart[3]));
}

__global__ void lncc_finalize_kernel(const double* __restrict__ acc,
                                     float* __restrict__ out) {
    const double n = (double)BB * HH * WW * DD;
    out[0] = (float)(-acc[0] / n);
}

extern "C" void kernel_launch(void* const* d_in, const int* in_sizes, int n_in,
                              void* d_out, int out_size, void* d_ws, size_t ws_size,
                              hipStream_t stream) {
    const float* pred = (const float*)d_in[0];
    const float* targ = (const float*)d_in[1];
    float* out = (float*)d_out;
    double* acc = (double*)d_ws;

    hipMemsetAsync(d_ws, 0, sizeof(double), stream);

    dim3 grid(DD / TX, WW / TY, BB * NSLAB);   // 12 x 12 x 14 = 2016 blocks
    dim3 block(TX, TY, 1);                     // 256 threads
    lncc_fused_kernel<<<grid, block, 0, stream>>>(pred, targ, acc);
    lncc_finalize_kernel<<<1, 1, 0, stream>>>(acc, out);
}